// Round 12
// baseline (259.543 us; speedup 1.0000x reference)
//
#include <hip/hip_runtime.h>

#define BATCH 8
#define CH    64
#define HH    112
#define WW    112
#define HW    (HH * WW)          // 12544
#define NP    (BATCH * HW)       // 100352 pixels
#define TAPS  25
#define MIDC  256
#define PIX   64                 // pixels per block (= 1 wave-width group)
#define CPW   16                 // channels per wave (4 waves * 16 = 64)
#define NBLK  (NP / PIX)         // 1568 blocks
#define NXCD  8
#define CPX   (NBLK / NXCD)      // 196 blocks per XCD == blocks per image

// ---------------------------------------------------------------------------
// Kernel A: fold conv2 (1x1, 256->25) into conv1 weights.  (verbatim R6)
//   weff[(c*TAPS+tap)*TAPS+o] = sum_mid w2[o][mid] * w1[mid][c][tap]
//   beff[o]                   = b2[o] + sum_mid w2[o][mid] * b1[mid]
// 626 blocks; 4 waves split K=256 into 64-wide chunks; 768B LDS reduce.
// ---------------------------------------------------------------------------
#define WEFF_N   (CH * TAPS * TAPS)   // 40000
#define WEFF_TOT (WEFF_N + TAPS)      // 40025 (beff appended)
__global__ __launch_bounds__(256) void weff_kernel(
    const float* __restrict__ w1, const float* __restrict__ b1,
    const float* __restrict__ w2, const float* __restrict__ b2,
    float* __restrict__ weff, float* __restrict__ beff) {
  __shared__ float part[3][64];              // chunks 1..3 park partials
  const int lane  = threadIdx.x & 63;
  const int chunk = threadIdx.x >> 6;        // mid in [chunk*64, chunk*64+64)
  const int id    = blockIdx.x * 64 + lane;

  float acc = 0.f;
  if (id < WEFF_N) {
    const int tap = id % TAPS;
    const int t2  = id / TAPS;
    const int o   = t2 % TAPS;
    const int c   = t2 / TAPS;
    const float* w2o = w2 + o * MIDC + chunk * 64;
    const float* w1p = w1 + ((size_t)(chunk * 64) * CH + c) * TAPS + tap;
    float a0 = 0.f, a1 = 0.f;
    #pragma unroll 8
    for (int m = 0; m < 64; m += 2) {
      a0 = fmaf(w1p[(size_t)m       * CH * TAPS], w2o[m],     a0);
      a1 = fmaf(w1p[(size_t)(m + 1) * CH * TAPS], w2o[m + 1], a1);
    }
    acc = a0 + a1;
  } else if (id < WEFF_TOT) {
    const int o = id - WEFF_N;
    const float* w2o = w2 + o * MIDC + chunk * 64;
    const float* b1p = b1 + chunk * 64;
    #pragma unroll 8
    for (int m = 0; m < 64; ++m) acc = fmaf(w2o[m], b1p[m], acc);
  }

  if (chunk) part[chunk - 1][lane] = acc;
  __syncthreads();
  if (chunk == 0 && id < WEFF_TOT) {
    float r = acc + part[0][lane] + part[1][lane] + part[2][lane];
    if (id < WEFF_N) {
      const int tap = id % TAPS;
      const int t2  = id / TAPS;
      const int o   = t2 % TAPS;
      const int c   = t2 / TAPS;
      weff[(c * TAPS + tap) * TAPS + o] = r;
    } else {
      beff[id - WEFF_N] = r + b2[id - WEFF_N];
    }
  }
}

// ---------------------------------------------------------------------------
// Kernel B. R12 = R6 phase 1 VERBATIM (s_load weights, branch-guarded taps,
// xv[16] batch) + simplified tail, isolated from R4's failed bundle:
//  - ONE barrier: all 4 waves store partials (25.6 KB), then EVERY thread
//    sums the 4 buffers + beff and computes softmax into REGISTERS.
//  - Phase 2 fully unrolled (compile-time i,j), sfin = s[t] static register
//    index, tap validity folded into s[t]=0. No LDS reads, no barriers 2-3.
//  - Nothing new lives across the barrier (R7-R9 spill killers absent).
// LDS 25.6 KB -> still 6 blocks/CU (160/25.6 = 6.25), same as R6.
// ---------------------------------------------------------------------------
__global__ __launch_bounds__(256, 6) void picanet_main(
    const float* __restrict__ x, const float* __restrict__ weff,
    const float* __restrict__ beff, float* __restrict__ out) {
  __shared__ float red[4 * PIX * TAPS];       // 25.6 KB

  const int lane = threadIdx.x & 63;
  const int wave = threadIdx.x >> 6;
  const int c0 = __builtin_amdgcn_readfirstlane(wave * CPW);

  // XCD-aware bijective remap: image b pinned to XCD b (3.2 MB < 4 MB L2).
  const int lb = (blockIdx.x & (NXCD - 1)) * CPX + (blockIdx.x >> 3);
  const int p  = lb * PIX + lane;             // NP % 64 == 0, no tail
  const int b  = p / HW;
  const int hw = p % HW;
  const int h  = hw / WW;
  const int w  = hw % WW;

  const float* xb = x + (size_t)b * CH * HW + (size_t)c0 * HW;
  const float* wc = weff + (size_t)c0 * (TAPS * TAPS);

  // ---- Phase 1: partial logits over this wave's 16 channels (R6) ----
  float s[TAPS];
  #pragma unroll
  for (int o = 0; o < TAPS; ++o) s[o] = 0.f;

  #pragma unroll 1
  for (int tap = 0; tap < TAPS; ++tap) {
    int i = tap / 5, j = tap % 5;
    int yy = h + 2 * i - 4;
    int xx = w + 2 * j - 4;
    if (yy >= 0 && yy < HH && xx >= 0 && xx < WW) {
      const float* xp = xb + yy * WW + xx;
      float xv[CPW];
      #pragma unroll
      for (int c = 0; c < CPW; ++c) xv[c] = xp[(size_t)c * HW];
      const float* wt = wc + tap * TAPS;
      #pragma unroll
      for (int c = 0; c < CPW; ++c) {
        const float* wp = wt + c * (TAPS * TAPS);   // uniform -> scalar loads
        #pragma unroll
        for (int o = 0; o < TAPS; ++o) s[o] = fmaf(xv[c], wp[o], s[o]);
      }
    }
  }

  // ---- Single barrier: all waves store partials ----
  #pragma unroll
  for (int o = 0; o < TAPS; ++o) red[(wave * PIX + lane) * TAPS + o] = s[o];
  __syncthreads();

  // ---- Softmax, redundantly per thread, entirely in registers ----
  // (stride-25 LDS rows: lane*25 mod 32 is a permutation -> conflict-free)
  float m = -1e30f;
  #pragma unroll
  for (int o = 0; o < TAPS; ++o) {
    float v = red[lane * TAPS + o] + red[(PIX + lane) * TAPS + o] +
              red[(2 * PIX + lane) * TAPS + o] +
              red[(3 * PIX + lane) * TAPS + o] + beff[o];
    s[o] = v;
    m = fmaxf(m, v);
  }
  float sum = 0.f;
  #pragma unroll
  for (int o = 0; o < TAPS; ++o) { s[o] = __expf(s[o] - m); sum += s[o]; }
  float inv = 1.f / sum;
  // Normalize + fold tap validity (denominator keeps all 25 taps, matching
  // the reference softmax; invalid taps contribute 0 in phase 2).
  #pragma unroll
  for (int o = 0; o < TAPS; ++o) {
    int i = o / 5, j = o % 5;                 // compile-time (unrolled)
    int yy = h + 2 * i - 4;
    int xx = w + 2 * j - 4;
    bool ok = (yy >= 0) & (yy < HH) & (xx >= 0) & (xx < WW);
    s[o] = ok ? s[o] * inv : 0.f;
  }

  // ---- Phase 2: fully unrolled, register weights, branch-free ----
  float acc[CPW];
  #pragma unroll
  for (int c = 0; c < CPW; ++c) acc[c] = 0.f;

  #pragma unroll
  for (int t = 0; t < TAPS; ++t) {
    int i = t / 5, j = t % 5;                 // compile-time (unrolled)
    int yy = h + 2 * i - 4;
    int xx = w + 2 * j - 4;
    bool ok = (yy >= 0) & (yy < HH) & (xx >= 0) & (xx < WW);
    int offt = ok ? yy * WW + xx : hw;        // s[t] == 0 when !ok
    float sv = s[t];                          // static register index
    #pragma unroll
    for (int c = 0; c < CPW; ++c)
      acc[c] = fmaf(sv, xb[(size_t)c * HW + offt], acc[c]);
  }

  float* ob = out + (size_t)b * CH * HW + (size_t)c0 * HW + hw;
  #pragma unroll
  for (int c = 0; c < CPW; ++c) ob[c * HW] = acc[c];
}

extern "C" void kernel_launch(void* const* d_in, const int* in_sizes, int n_in,
                              void* d_out, int out_size, void* d_ws, size_t ws_size,
                              hipStream_t stream) {
  const float* x  = (const float*)d_in[0];
  const float* w1 = (const float*)d_in[1];
  const float* b1 = (const float*)d_in[2];
  const float* w2 = (const float*)d_in[3];
  const float* b2 = (const float*)d_in[4];
  float* out  = (float*)d_out;
  float* weff = (float*)d_ws;                       // 40000 floats
  float* beff = weff + WEFF_N;                      // 25 floats

  weff_kernel<<<(WEFF_TOT + 63) / 64, 256, 0, stream>>>(
      w1, b1, w2, b2, weff, beff);
  picanet_main<<<NBLK, 256, 0, stream>>>(x, weff, beff, out);
}